// Round 1
// baseline (242.138 us; speedup 1.0000x reference)
//
#include <hip/hip_runtime.h>
#include <cstdint>

typedef short bf16x8 __attribute__((ext_vector_type(8)));
typedef float f32x4 __attribute__((ext_vector_type(4)));
typedef unsigned short u16;

#define BATCH 2
#define NTOK 2048
#define CDIM 1024
#define NHEAD 16
#define DHEAD 64
#define MROWS 4096   // B*N
#define KDIM 1024

__device__ __forceinline__ u16 f2bf(float x) {
    uint32_t b = __float_as_uint(x);
    uint32_t r = (b + 0x7fffu + ((b >> 16) & 1u)) >> 16;
    return (u16)r;
}

__device__ __forceinline__ void gload_lds16(const void* g, void* l) {
    __builtin_amdgcn_global_load_lds((const __attribute__((address_space(1))) void*)g,
                                     (__attribute__((address_space(3))) void*)l,
                                     16, 0, 0);
}

// ---------------- cast fp32 -> bf16 (inputs + weights, 16M elems) ----------------
__global__ __launch_bounds__(256) void cast_kernel(
    const float* __restrict__ q, const float* __restrict__ k, const float* __restrict__ v,
    const float* __restrict__ wq, const float* __restrict__ wk, const float* __restrict__ wv,
    const float* __restrict__ wo, u16* __restrict__ dst) {
    const size_t TOT = 16u << 20;
    size_t i0 = ((size_t)blockIdx.x * 256 + threadIdx.x) * 4;
    size_t stride = (size_t)gridDim.x * 256 * 4;
    for (size_t i = i0; i < TOT; i += stride) {
        const float* src;
        size_t off = i;
        if (i < (4u << 20))        { src = q;  }
        else if (i < (8u << 20))   { src = k;  off = i - (4u << 20); }
        else if (i < (12u << 20))  { src = v;  off = i - (8u << 20); }
        else if (i < (13u << 20))  { src = wq; off = i - (12u << 20); }
        else if (i < (14u << 20))  { src = wk; off = i - (13u << 20); }
        else if (i < (15u << 20))  { src = wv; off = i - (14u << 20); }
        else                       { src = wo; off = i - (15u << 20); }
        float4 f = *(const float4*)(src + off);
        u16 o0 = f2bf(f.x), o1 = f2bf(f.y), o2 = f2bf(f.z), o3 = f2bf(f.w);
        uint2 packed;
        packed.x = (uint32_t)o0 | ((uint32_t)o1 << 16);
        packed.y = (uint32_t)o2 | ((uint32_t)o3 << 16);
        *(uint2*)(dst + i) = packed;
    }
}

// ---------------- GEMM: C[m,n] = sum_k A[m,k]*W[n,k] + bias[n] ----------------
// MODE 0: write bf16 into QKV layout [B*H][NTOK][DHEAD]
// MODE 1: write fp32 into [M][N]
template<int MODE>
__global__ __launch_bounds__(256, 2) void gemm_bt(
    const u16* __restrict__ A,   // [M,K] bf16
    const u16* __restrict__ Bw,  // [N,K] bf16
    const float* __restrict__ bias,
    void* __restrict__ Cout,
    int M, int N, int K) {
    __shared__ u16 sA[128 * 32];
    __shared__ u16 sB[128 * 32];
    const int tid = threadIdx.x;
    const int lane = tid & 63;
    const int wave = tid >> 6;
    const int m0 = blockIdx.x * 128, n0 = blockIdx.y * 128;
    const int wm = (wave >> 1) * 64, wn = (wave & 1) * 64;
    f32x4 acc[4][4] = {};

    const int rsel = lane & 15;
    const int ksel = (lane >> 4) * 8;

    for (int k0 = 0; k0 < K; k0 += 32) {
#pragma unroll
        for (int u = 0; u < 2; ++u) {
            int c = tid + u * 256;          // 512 chunks of 16B
            int row = c >> 2, cin = c & 3;
            gload_lds16(A + (size_t)(m0 + row) * K + k0 + cin * 8, &sA[c * 8]);
            gload_lds16(Bw + (size_t)(n0 + row) * K + k0 + cin * 8, &sB[c * 8]);
        }
        __syncthreads();
        bf16x8 af[4], bfr[4];
#pragma unroll
        for (int i = 0; i < 4; ++i)
            af[i] = *(const bf16x8*)&sA[(wm + i * 16 + rsel) * 32 + ksel];
#pragma unroll
        for (int j = 0; j < 4; ++j)
            bfr[j] = *(const bf16x8*)&sB[(wn + j * 16 + rsel) * 32 + ksel];
#pragma unroll
        for (int i = 0; i < 4; ++i)
#pragma unroll
            for (int j = 0; j < 4; ++j)
                acc[i][j] = __builtin_amdgcn_mfma_f32_16x16x32_bf16(af[i], bfr[j], acc[i][j], 0, 0, 0);
        __syncthreads();
    }

    if (MODE == 0) {
        u16* Out = (u16*)Cout;  // [B*H][NTOK][DHEAD]
#pragma unroll
        for (int i = 0; i < 4; ++i) {
            int mbase = m0 + wm + i * 16 + (lane >> 4) * 4;
#pragma unroll
            for (int j = 0; j < 4; ++j) {
                int n = n0 + wn + j * 16 + (lane & 15);
                float bv = bias[n];
                int h = n >> 6, d = n & 63;
#pragma unroll
                for (int r = 0; r < 4; ++r) {
                    int m = mbase + r;
                    int b = m >> 11, tok = m & 2047;
                    Out[(((size_t)(b * NHEAD + h)) * NTOK + tok) * DHEAD + d] =
                        f2bf(acc[i][j][r] + bv);
                }
            }
        }
    } else {
        float* Out = (float*)Cout;
#pragma unroll
        for (int i = 0; i < 4; ++i) {
            int mbase = m0 + wm + i * 16 + (lane >> 4) * 4;
#pragma unroll
            for (int j = 0; j < 4; ++j) {
                int n = n0 + wn + j * 16 + (lane & 15);
                float bv = bias[n];
#pragma unroll
                for (int r = 0; r < 4; ++r) {
                    int m = mbase + r;
                    Out[(size_t)m * N + n] = acc[i][j][r] + bv;
                }
            }
        }
    }
}

// ---------------- flash attention ----------------
// grid: (NTOK/64, B*H); 4 waves per block, 16 q-rows per wave; KV tiles of 64.
__global__ __launch_bounds__(256, 3) void attn_kernel(
    const u16* __restrict__ Qg, const u16* __restrict__ Kg, const u16* __restrict__ Vg,
    u16* __restrict__ Og) {     // Og: [B*NTOK][CDIM] bf16
    __shared__ u16 Ks[64 * 64];       // row-major, XOR-swizzled via source addresses
    __shared__ u16 Vt[64][88];        // Vt[d][j] = V[j][d], padded stride
    __shared__ u16 Ps[4][16][88];     // per-wave P tile [q][j]
    const int tid = threadIdx.x, lane = tid & 63, wave = tid >> 6;
    const int bh = blockIdx.y;
    const int h = bh & (NHEAD - 1), b = bh >> 4;
    const u16* Qh = Qg + (size_t)bh * NTOK * DHEAD;
    const u16* Kh = Kg + (size_t)bh * NTOK * DHEAD;
    const u16* Vh = Vg + (size_t)bh * NTOK * DHEAD;
    const int qrow0 = blockIdx.x * 64 + wave * 16;

    bf16x8 qf[2];
    {
        int qr = qrow0 + (lane & 15);
        int d0 = (lane >> 4) * 8;
        qf[0] = *(const bf16x8*)&Qh[(size_t)qr * DHEAD + d0];
        qf[1] = *(const bf16x8*)&Qh[(size_t)qr * DHEAD + 32 + d0];
    }

    f32x4 acc[4] = {};
    float mrun[4], lrun[4];
#pragma unroll
    for (int r = 0; r < 4; ++r) { mrun[r] = -1e30f; lrun[r] = 0.f; }

    for (int t0 = 0; t0 < NTOK; t0 += 64) {
        // stage K tile: linear LDS, swizzled global source (byte ^= (row&7)<<4)
#pragma unroll
        for (int u = 0; u < 2; ++u) {
            int c = tid + u * 256;        // 512 chunks of 16B
            int row = c >> 3, cin = c & 7;
            int scin = cin ^ (row & 7);
            gload_lds16(Kh + (size_t)(t0 + row) * DHEAD + scin * 8, &Ks[c * 8]);
        }
        // stage V transposed (reg-staged)
        {
            int j = tid >> 2, d0 = (tid & 3) * 16;
            const u16* vp = Vh + (size_t)(t0 + j) * DHEAD + d0;
            uint4 vv0 = *(const uint4*)(vp);
            uint4 vv1 = *(const uint4*)(vp + 8);
            uint32_t v32[8] = {vv0.x, vv0.y, vv0.z, vv0.w, vv1.x, vv1.y, vv1.z, vv1.w};
#pragma unroll
            for (int i = 0; i < 8; ++i) {
                Vt[d0 + 2 * i][j]     = (u16)(v32[i] & 0xffffu);
                Vt[d0 + 2 * i + 1][j] = (u16)(v32[i] >> 16);
            }
        }
        __syncthreads();

        // S = Q K^T * 0.125
        f32x4 s[4];
#pragma unroll
        for (int nb = 0; nb < 4; ++nb) {
            f32x4 as = {};
#pragma unroll
            for (int ks = 0; ks < 2; ++ks) {
                int row = nb * 16 + (lane & 15);
                int byteoff = row * 128 + (ks * 32 + (lane >> 4) * 8) * 2;
                byteoff ^= (row & 7) << 4;
                bf16x8 kf = *(const bf16x8*)((const char*)Ks + byteoff);
                as = __builtin_amdgcn_mfma_f32_16x16x32_bf16(qf[ks], kf, as, 0, 0, 0);
            }
            s[nb] = as * 0.125f;
        }
        // online softmax: row max across 16 lanes of the group
        float scl[4];
#pragma unroll
        for (int r = 0; r < 4; ++r) {
            float v = fmaxf(fmaxf(s[0][r], s[1][r]), fmaxf(s[2][r], s[3][r]));
            v = fmaxf(v, __shfl_xor(v, 1));
            v = fmaxf(v, __shfl_xor(v, 2));
            v = fmaxf(v, __shfl_xor(v, 4));
            v = fmaxf(v, __shfl_xor(v, 8));
            float mnew = fmaxf(mrun[r], v);
            scl[r] = __expf(mrun[r] - mnew);
            mrun[r] = mnew;
        }
        float psum[4] = {0.f, 0.f, 0.f, 0.f};
#pragma unroll
        for (int nb = 0; nb < 4; ++nb) {
#pragma unroll
            for (int r = 0; r < 4; ++r) {
                float p = __expf(s[nb][r] - mrun[r]);
                psum[r] += p;
                Ps[wave][(lane >> 4) * 4 + r][nb * 16 + (lane & 15)] = f2bf(p);
            }
        }
#pragma unroll
        for (int r = 0; r < 4; ++r) {
            float v = psum[r];
            v += __shfl_xor(v, 1);
            v += __shfl_xor(v, 2);
            v += __shfl_xor(v, 4);
            v += __shfl_xor(v, 8);
            lrun[r] = lrun[r] * scl[r] + v;
        }
#pragma unroll
        for (int dblk = 0; dblk < 4; ++dblk)
#pragma unroll
            for (int r = 0; r < 4; ++r)
                acc[dblk][r] *= scl[r];
        asm volatile("s_waitcnt lgkmcnt(0)" ::: "memory");
        // PV
#pragma unroll
        for (int dblk = 0; dblk < 4; ++dblk) {
#pragma unroll
            for (int ks = 0; ks < 2; ++ks) {
                bf16x8 pa = *(const bf16x8*)&Ps[wave][lane & 15][ks * 32 + (lane >> 4) * 8];
                bf16x8 vb = *(const bf16x8*)&Vt[dblk * 16 + (lane & 15)][ks * 32 + (lane >> 4) * 8];
                acc[dblk] = __builtin_amdgcn_mfma_f32_16x16x32_bf16(pa, vb, acc[dblk], 0, 0, 0);
            }
        }
        __syncthreads();
    }

    // epilogue: O[b, q, h*64+d] = acc / l
#pragma unroll
    for (int dblk = 0; dblk < 4; ++dblk) {
        int d = dblk * 16 + (lane & 15);
#pragma unroll
        for (int r = 0; r < 4; ++r) {
            int q = qrow0 + (lane >> 4) * 4 + r;
            float o = acc[dblk][r] / lrun[r];
            Og[((size_t)(b * NTOK + q)) * CDIM + h * DHEAD + d] = f2bf(o);
        }
    }
}

extern "C" void kernel_launch(void* const* d_in, const int* in_sizes, int n_in,
                              void* d_out, int out_size, void* d_ws, size_t ws_size,
                              hipStream_t stream) {
    const float* q  = (const float*)d_in[0];
    const float* k  = (const float*)d_in[1];
    const float* v  = (const float*)d_in[2];
    const float* Wq = (const float*)d_in[3];
    const float* bq = (const float*)d_in[4];
    const float* Wk = (const float*)d_in[5];
    const float* bk = (const float*)d_in[6];
    const float* Wv = (const float*)d_in[7];
    const float* bv = (const float*)d_in[8];
    const float* Wo = (const float*)d_in[9];
    const float* bo = (const float*)d_in[10];

    u16* wsp = (u16*)d_ws;
    u16* Xq  = wsp;                     // 4M elems (bf16 query)
    u16* Xk  = Xq + (4u << 20);
    u16* Xv  = Xk + (4u << 20);
    u16* Wqb = Xv + (4u << 20);         // 1M elems each
    u16* Wkb = Wqb + (1u << 20);
    u16* Wvb = Wkb + (1u << 20);
    u16* Wob = Wvb + (1u << 20);
    u16* Qb  = Wob + (1u << 20);        // [B*H][N][D] bf16, 4M elems
    u16* Kb  = Qb + (4u << 20);
    u16* Vb  = Kb + (4u << 20);
    u16* Ab  = Xq;                      // reuse query-cast region for attn output

    cast_kernel<<<2048, 256, 0, stream>>>(q, k, v, Wq, Wk, Wv, Wo, Xq);

    dim3 gproj(MROWS / 128, CDIM / 128);
    gemm_bt<0><<<gproj, 256, 0, stream>>>(Xq, Wqb, bq, Qb, MROWS, CDIM, KDIM);
    gemm_bt<0><<<gproj, 256, 0, stream>>>(Xk, Wkb, bk, Kb, MROWS, CDIM, KDIM);
    gemm_bt<0><<<gproj, 256, 0, stream>>>(Xv, Wvb, bv, Vb, MROWS, CDIM, KDIM);

    attn_kernel<<<dim3(NTOK / 64, BATCH * NHEAD), 256, 0, stream>>>(Qb, Kb, Vb, Ab);

    gemm_bt<1><<<gproj, 256, 0, stream>>>(Ab, Wob, bo, d_out, MROWS, CDIM, KDIM);
}